// Round 2
// baseline (416.550 us; speedup 1.0000x reference)
//
#include <hip/hip_runtime.h>
#include <cstdint>

#define A_DIM 1024
#define B_DIM 64
#define H_DIM 512
#define L_TXT 1024
#define L_IMG 256

typedef float f32x4 __attribute__((ext_vector_type(4)));

// ---------------- ws layout (float offsets) ----------------
//   P4 : (1024 + 256) * 1024 = 1,310,720   (ctx partials, at offset 0)
#define WS_DF_OFF   1310720u   // df/dfi/g3/g4 : 4*64*1024 = 262,144
#define WS_E_OFF    1572864u   // e (65536) + e_img (16384) = 81,920
#define WS_CTX_OFF  1654784u   // ctx_t (65536) + ctx_i (65536)
// total = 1,785,856 floats = ~7.2 MB

// d_out layout (floats): ctx_mm[0..65535], attn[65536..131071],
// attn_img[131072..147455], coverage[147456..212991], coverage_img[212992..229375]

__device__ __forceinline__ float ftanh(float x) {
  float xc = fminf(fmaxf(x, -10.f), 10.f);
  float t  = __expf(2.f * xc);
  return (t - 1.f) * __builtin_amdgcn_rcpf(t + 1.f);
}

// K1 (fused): df_all[m][b][a] = (dec @ Wm)[b][a] + bias_m[a].
// grid = 256 blocks (m, a-tile16), block = 256 thr = 4 waves (k-quarters).
__global__ __launch_bounds__(256) void k1_gemm_dec(
    const float* __restrict__ h0, const float* __restrict__ h1,
    const float* __restrict__ W1, const float* __restrict__ W2,
    const float* __restrict__ W3, const float* __restrict__ W4,
    const float* __restrict__ b1, const float* __restrict__ b2,
    const float* __restrict__ b3, const float* __restrict__ b4,
    float* __restrict__ df_all) {
  __shared__ float lds[4][64][17];
  int bid  = blockIdx.x;            // 0..255
  int m    = bid >> 6;              // 0..3
  int at   = bid & 63;              // 0..63
  int kq   = threadIdx.x >> 6;      // 0..3
  int lane = threadIdx.x & 63;      // == b
  const float* W    = (m == 0) ? W1 : (m == 1) ? W2 : (m == 2) ? W3 : W4;
  const float* bias = (m == 0) ? b1 : (m == 1) ? b2 : (m == 2) ? b3 : b4;
  int a0 = at * 16;
  int k0 = kq * 256;
  const float* dsrc = (k0 < 512) ? (h0 + lane * H_DIM + k0)
                                 : (h1 + lane * H_DIM + (k0 - 512));
  float acc[16];
#pragma unroll
  for (int t = 0; t < 16; ++t) acc[t] = 0.f;

  for (int kc = 0; kc < 16; ++kc) {
    const float4* dp = reinterpret_cast<const float4*>(dsrc + kc * 16);
    float4 d0 = dp[0], d1 = dp[1], d2 = dp[2], d3 = dp[3];
    float dk[16] = {d0.x, d0.y, d0.z, d0.w, d1.x, d1.y, d1.z, d1.w,
                    d2.x, d2.y, d2.z, d2.w, d3.x, d3.y, d3.z, d3.w};
    const float* Wp = W + (size_t)(k0 + kc * 16) * A_DIM + a0;
#pragma unroll
    for (int j = 0; j < 16; ++j) {
#pragma unroll
      for (int t = 0; t < 16; ++t)
        acc[t] = fmaf(dk[j], Wp[(size_t)j * A_DIM + t], acc[t]);  // W uniform -> s_load
    }
  }
#pragma unroll
  for (int t = 0; t < 16; ++t) lds[kq][lane][t] = acc[t];
  __syncthreads();
#pragma unroll
  for (int k = 0; k < 4; ++k) {
    int e = threadIdx.x + k * 256;   // 0..1023
    int b = e >> 4, t = e & 15;
    float s = lds[0][b][t] + lds[1][b][t] + lds[2][b][t] + lds[3][b][t];
    df_all[(size_t)m * 65536 + (size_t)b * 1024 + a0 + t] = s + bias[a0 + t];
  }
}

// K2: e[b,l] = sum_a v[a]*tanh(feat + df + cov*wc).
// block = (b, 64-row chunk); wave w handles 16 rows; df/v/wc cached in regs.
// blocks 0..1023 text, 1024..1279 img.
__global__ __launch_bounds__(256) void k2_energy(
    const float* __restrict__ enc_features, const float* __restrict__ enc_img_features,
    const float* __restrict__ coverage, const float* __restrict__ coverage_img,
    const float* __restrict__ df_all,
    const float* __restrict__ v1, const float* __restrict__ v2,
    const float* __restrict__ wc, const float* __restrict__ wci,
    const int* __restrict__ cov_set_p,
    float* __restrict__ e_all) {
  int bid  = blockIdx.x;
  int w    = threadIdx.x >> 6;
  int lane = threadIdx.x & 63;
  float covscale = (float)(*cov_set_p);
  const float *feat, *covsrc, *dfp, *vv, *wcp;
  float* eout;
  if (bid < 1024) {
    int b = bid >> 4, chunk = bid & 15;
    int row0 = chunk * 64 + w * 16;
    feat   = enc_features + ((size_t)b * 1024 + row0) * 1024;
    covsrc = coverage + (size_t)b * 1024 + row0;
    eout   = e_all + (size_t)b * 1024 + row0;
    dfp    = df_all + (size_t)b * 1024;
    vv = v1; wcp = wc;
  } else {
    int bi = bid - 1024;
    int b = bi >> 2, chunk = bi & 3;
    int row0 = chunk * 64 + w * 16;
    feat   = enc_img_features + ((size_t)b * 256 + row0) * 1024;
    covsrc = coverage_img + (size_t)b * 256 + row0;
    eout   = e_all + 65536 + (size_t)b * 256 + row0;
    dfp    = df_all + 65536 + (size_t)b * 1024;
    vv = v2; wcp = wci;
  }
  f32x4 dfv[4], vvv[4], wcv[4];
#pragma unroll
  for (int p = 0; p < 4; ++p) {
    int a = p * 256 + lane * 4;
    dfv[p] = *reinterpret_cast<const f32x4*>(dfp + a);
    vvv[p] = *reinterpret_cast<const f32x4*>(vv + a);
    wcv[p] = *reinterpret_cast<const f32x4*>(wcp + a);
  }
#pragma unroll 2
  for (int r = 0; r < 16; ++r) {
    float cov = covsrc[r] * covscale;
    float acc = 0.f;
#pragma unroll
    for (int p = 0; p < 4; ++p) {
      const f32x4* fp = reinterpret_cast<const f32x4*>(
          feat + (size_t)r * 1024 + p * 256 + lane * 4);
      f32x4 f = __builtin_nontemporal_load(fp);
      f32x4 x = f + dfv[p] + cov * wcv[p];
      acc += vvv[p].x * ftanh(x.x);
      acc += vvv[p].y * ftanh(x.y);
      acc += vvv[p].z * ftanh(x.z);
      acc += vvv[p].w * ftanh(x.w);
    }
#pragma unroll
    for (int o = 32; o > 0; o >>= 1) acc += __shfl_xor(acc, o);
    if (lane == 0) eout[r] = acc;
  }
}

// K3: per-row softmax (+mask renorm for text) + attn & coverage outputs.
__global__ __launch_bounds__(256) void k3_softmax(
    const float* __restrict__ e_all, const float* __restrict__ enc_mask,
    const float* __restrict__ coverage, const float* __restrict__ coverage_img,
    const int* __restrict__ cov_set_p,
    float* __restrict__ out) {
  __shared__ float red[8];
  int bid = blockIdx.x;
  int tid = threadIdx.x;
  float covscale = (float)(*cov_set_p);
  int nk;
  const float *e, *mask, *covin;
  float *attn_out, *cov_out;
  if (bid < 64) {
    nk = 4;
    e = e_all + (size_t)bid * 1024;
    mask = enc_mask + (size_t)bid * 1024;
    covin = coverage + (size_t)bid * 1024;
    attn_out = out + 65536 + (size_t)bid * 1024;
    cov_out  = out + 147456 + (size_t)bid * 1024;
  } else {
    int b = bid - 64;
    nk = 1;
    e = e_all + 65536 + (size_t)b * 256;
    mask = nullptr;
    covin = coverage_img + (size_t)b * 256;
    attn_out = out + 131072 + (size_t)b * 256;
    cov_out  = out + 212992 + (size_t)b * 256;
  }
  float ev[4], mv[4];
  float mx = -1e30f;
  for (int k = 0; k < nk; ++k) {
    int i = k * 256 + tid;
    ev[k] = e[i];
    mv[k] = mask ? mask[i] : 1.f;
    mx = fmaxf(mx, ev[k]);
  }
#pragma unroll
  for (int o = 32; o > 0; o >>= 1) mx = fmaxf(mx, __shfl_xor(mx, o));
  if ((tid & 63) == 0) red[tid >> 6] = mx;
  __syncthreads();
  mx = fmaxf(fmaxf(red[0], red[1]), fmaxf(red[2], red[3]));
  float pv[4];
  float s = 0.f;
  for (int k = 0; k < nk; ++k) {
    pv[k] = __expf(ev[k] - mx) * mv[k];
    s += pv[k];
  }
#pragma unroll
  for (int o = 32; o > 0; o >>= 1) s += __shfl_xor(s, o);
  if ((tid & 63) == 0) red[4 + (tid >> 6)] = s;
  __syncthreads();
  s = red[4] + red[5] + red[6] + red[7];
  float inv = 1.f / s;
  for (int k = 0; k < nk; ++k) {
    int i = k * 256 + tid;
    float at = pv[k] * inv;
    attn_out[i] = at;
    cov_out[i] = covscale * covin[i] + at;  // covscale==0 -> coverage = attn
  }
}

// K4: ctx partials. block = (b, 64-row L chunk); 256 thr * float4 = full A row.
__global__ __launch_bounds__(256) void k4_ctx_partial(
    const float* __restrict__ enc_outputs, const float* __restrict__ enc_img_outputs,
    const float* __restrict__ out, float* __restrict__ P4) {
  int bid = blockIdx.x;
  int tid = threadIdx.x;
  const float *src, *attn;
  if (bid < 1024) {
    int b = bid >> 4, c = bid & 15;
    src  = enc_outputs + ((size_t)b * 1024 + c * 64) * 1024;
    attn = out + 65536 + (size_t)b * 1024 + c * 64;
  } else {
    int bi = bid - 1024;
    int b = bi >> 2, c = bi & 3;
    src  = enc_img_outputs + ((size_t)b * 256 + c * 64) * 1024;
    attn = out + 131072 + (size_t)b * 256 + c * 64;
  }
  const f32x4* srcp = reinterpret_cast<const f32x4*>(src) + tid;
  f32x4 acc = {0.f, 0.f, 0.f, 0.f};
#pragma unroll 8
  for (int l = 0; l < 64; ++l) {
    float w = attn[l];  // wave-uniform -> s_load
    f32x4 r = __builtin_nontemporal_load(srcp + (size_t)l * 256);
    acc += w * r;
  }
  *reinterpret_cast<f32x4*>(P4 + (size_t)bid * 1024 + tid * 4) = acc;
}

// K4b: ctx_t[b][a] = sum_{16 chunks}; ctx_i[b][a] = sum_{4 chunks}
__global__ __launch_bounds__(256) void k4b_reduce(const float* __restrict__ P4,
                                                  float* __restrict__ ctx) {
  int tid = blockIdx.x * 256 + threadIdx.x;  // 0..131071
  int which = tid >> 16;
  int b = (tid >> 10) & 63;
  int a = tid & 1023;
  float s = 0.f;
  if (which == 0) {
    const float* p = P4 + ((size_t)b * 16) * 1024 + a;
#pragma unroll
    for (int c = 0; c < 16; ++c) s += p[(size_t)c * 1024];
    ctx[(size_t)b * 1024 + a] = s;
  } else {
    const float* p = P4 + ((size_t)1024 + b * 4) * 1024 + a;
#pragma unroll
    for (int c = 0; c < 4; ++c) s += p[(size_t)c * 1024];
    ctx[65536 + (size_t)b * 1024 + a] = s;
  }
}

// K5 (fused): ctx_mm = v3*tanh(g3+ctx_t@WA)*ctx_t + v4*tanh(g4+ctx_i@WB)*ctx_i
// grid = 64 blocks (a-tile16), block = 512 thr = 8 waves (m 0..1 x kq 0..3).
__global__ __launch_bounds__(512) void k5_fused(
    const float* __restrict__ ctx,
    const float* __restrict__ WA, const float* __restrict__ WB,
    const float* __restrict__ df_all,
    const float* __restrict__ v3, const float* __restrict__ v4,
    float* __restrict__ out) {
  __shared__ float lds[2][4][64][17];
  int at   = blockIdx.x;            // 0..63
  int wid  = threadIdx.x >> 6;      // 0..7
  int m    = wid >> 2;
  int kq   = wid & 3;
  int lane = threadIdx.x & 63;      // == b
  const float* W = m ? WB : WA;
  int a0 = at * 16;
  int k0 = kq * 256;
  const float* csrc = ctx + (size_t)m * 65536 + (size_t)lane * 1024 + k0;
  float acc[16];
#pragma unroll
  for (int t = 0; t < 16; ++t) acc[t] = 0.f;
  for (int kc = 0; kc < 16; ++kc) {
    const float4* dp = reinterpret_cast<const float4*>(csrc + kc * 16);
    float4 d0 = dp[0], d1 = dp[1], d2 = dp[2], d3 = dp[3];
    float dk[16] = {d0.x, d0.y, d0.z, d0.w, d1.x, d1.y, d1.z, d1.w,
                    d2.x, d2.y, d2.z, d2.w, d3.x, d3.y, d3.z, d3.w};
    const float* Wp = W + (size_t)(k0 + kc * 16) * A_DIM + a0;
#pragma unroll
    for (int j = 0; j < 16; ++j) {
#pragma unroll
      for (int t = 0; t < 16; ++t)
        acc[t] = fmaf(dk[j], Wp[(size_t)j * A_DIM + t], acc[t]);
    }
  }
#pragma unroll
  for (int t = 0; t < 16; ++t) lds[m][kq][lane][t] = acc[t];
  __syncthreads();
#pragma unroll
  for (int k = 0; k < 2; ++k) {
    int e = threadIdx.x + k * 512;   // 0..1023
    int b = e >> 4, t = e & 15;
    float sA = lds[0][0][b][t] + lds[0][1][b][t] + lds[0][2][b][t] + lds[0][3][b][t];
    float sB = lds[1][0][b][t] + lds[1][1][b][t] + lds[1][2][b][t] + lds[1][3][b][t];
    int a = a0 + t;
    size_t base = (size_t)b * 1024 + a;
    float ct  = ctx[base];
    float ci  = ctx[65536 + base];
    float g3v = df_all[131072 + base];
    float g4v = df_all[196608 + base];
    float beta1 = v3[a] * ftanh(g3v + sA);
    float beta2 = v4[a] * ftanh(g4v + sB);
    out[base] = beta1 * ct + beta2 * ci;
  }
}

extern "C" void kernel_launch(void* const* d_in, const int* in_sizes, int n_in,
                              void* d_out, int out_size, void* d_ws, size_t ws_size,
                              hipStream_t stream) {
  const float* h0            = (const float*)d_in[0];
  const float* h1            = (const float*)d_in[1];
  const float* enc_outputs   = (const float*)d_in[2];
  const float* enc_features  = (const float*)d_in[3];
  const float* enc_mask      = (const float*)d_in[4];
  const float* coverage      = (const float*)d_in[5];
  const float* enc_img_outs  = (const float*)d_in[6];
  const float* enc_img_feats = (const float*)d_in[7];
  // d_in[8] = img_mask (unused by reference)
  const float* coverage_img  = (const float*)d_in[9];
  const int*   cov_set       = (const int*)d_in[10];
  const float* W1 = (const float*)d_in[11];
  const float* b1 = (const float*)d_in[12];
  const float* W2 = (const float*)d_in[13];
  const float* b2 = (const float*)d_in[14];
  const float* W3 = (const float*)d_in[15];
  const float* b3 = (const float*)d_in[16];
  const float* W4 = (const float*)d_in[17];
  const float* b4 = (const float*)d_in[18];
  const float* WA = (const float*)d_in[19];
  const float* WB = (const float*)d_in[20];
  const float* v1 = (const float*)d_in[21];
  const float* v2 = (const float*)d_in[22];
  const float* v3 = (const float*)d_in[23];
  const float* v4 = (const float*)d_in[24];
  const float* wc  = (const float*)d_in[25];
  const float* wci = (const float*)d_in[26];

  float* out = (float*)d_out;
  float* ws  = (float*)d_ws;

  float* P4     = ws;
  float* df_all = ws + WS_DF_OFF;
  float* e_all  = ws + WS_E_OFF;
  float* ctx    = ws + WS_CTX_OFF;

  k1_gemm_dec<<<dim3(256), dim3(256), 0, stream>>>(h0, h1, W1, W2, W3, W4,
                                                   b1, b2, b3, b4, df_all);
  k2_energy<<<dim3(1280), dim3(256), 0, stream>>>(enc_features, enc_img_feats,
                                                  coverage, coverage_img, df_all,
                                                  v1, v2, wc, wci, cov_set, e_all);
  k3_softmax<<<dim3(128), dim3(256), 0, stream>>>(e_all, enc_mask, coverage,
                                                  coverage_img, cov_set, out);
  k4_ctx_partial<<<dim3(1280), dim3(256), 0, stream>>>(enc_outputs, enc_img_outs,
                                                       out, P4);
  k4b_reduce<<<dim3(512), dim3(256), 0, stream>>>(P4, ctx);
  k5_fused<<<dim3(64), dim3(512), 0, stream>>>(ctx, WA, WB, df_all, v3, v4, out);
}

// Round 3
// 197.603 us; speedup vs baseline: 2.1080x; 2.1080x over previous
//
#include <hip/hip_runtime.h>
#include <cstdint>

#define A_DIM 1024
#define B_DIM 64
#define H_DIM 512
#define L_TXT 1024
#define L_IMG 256

typedef float f32x4 __attribute__((ext_vector_type(4)));

// ---------------- ws layout (float offsets) ----------------
// region P (scratch, disjoint lifetimes):
//   P1 : 4 mats * 4 kq * 64 * 1024 = 1,048,576
//   P4 : (1024 + 256) * 1024       = 1,310,720  (max)
//   P5 : 2 mats * 4 kq * 64 * 1024 =   524,288
#define WS_DF_OFF   1310720u   // df/dfi/g3/g4 : 4*64*1024 = 262,144
#define WS_E_OFF    1572864u   // e (65536) + e_img (16384)
#define WS_CTX_OFF  1654784u   // ctx_t (65536) + ctx_i (65536)

// d_out layout (floats): ctx_mm[0..65535], attn[65536..131071],
// attn_img[131072..147455], coverage[147456..212991], coverage_img[212992..229375]

__device__ __forceinline__ float ftanh(float x) {
  float xc = fminf(fmaxf(x, -10.f), 10.f);
  float t  = __expf(2.f * xc);
  return (t - 1.f) * __builtin_amdgcn_rcpf(t + 1.f);
}

// K1: partials of dec @ {W1..W4}. W rows loaded VECTOR-coalesced (lane = a/4),
// dec loaded as uniform sequential s_loads. grid = 128 blocks (m, bg, kq).
__global__ __launch_bounds__(256) void k1_gemm(
    const float* __restrict__ h0, const float* __restrict__ h1,
    const float* __restrict__ W1, const float* __restrict__ W2,
    const float* __restrict__ W3, const float* __restrict__ W4,
    float* __restrict__ P1) {
  int bid = blockIdx.x;            // 0..127
  int m   = bid >> 5;              // 0..3
  int bg  = (bid >> 2) & 7;        // 0..7 (8 batch rows each)
  int kq  = bid & 3;               // 0..3 (k-quarter of 256)
  const float* W = (m == 0) ? W1 : (m == 1) ? W2 : (m == 2) ? W3 : W4;
  // dec[b][k] = k<512 ? h0[b][k] : h1[b][k-512]; quarter stays in one half.
  const float* dbase = ((kq < 2) ? h0 : h1) + (kq & 1) * 256;
  const float* Wrow  = W + (size_t)(kq * 256) * A_DIM + threadIdx.x * 4;

  f32x4 acc[8];
#pragma unroll
  for (int i = 0; i < 8; ++i) acc[i] = (f32x4){0.f, 0.f, 0.f, 0.f};

  for (int k4 = 0; k4 < 256; k4 += 4) {
    f32x4 w0 = *reinterpret_cast<const f32x4*>(Wrow + (size_t)(k4 + 0) * A_DIM);
    f32x4 w1 = *reinterpret_cast<const f32x4*>(Wrow + (size_t)(k4 + 1) * A_DIM);
    f32x4 w2 = *reinterpret_cast<const f32x4*>(Wrow + (size_t)(k4 + 2) * A_DIM);
    f32x4 w3 = *reinterpret_cast<const f32x4*>(Wrow + (size_t)(k4 + 3) * A_DIM);
#pragma unroll
    for (int i = 0; i < 8; ++i) {
      int b = bg * 8 + i;
      f32x4 d = *reinterpret_cast<const f32x4*>(dbase + (size_t)b * H_DIM + k4);
      acc[i] += d.x * w0;
      acc[i] += d.y * w1;
      acc[i] += d.z * w2;
      acc[i] += d.w * w3;
    }
  }
#pragma unroll
  for (int i = 0; i < 8; ++i) {
    int b = bg * 8 + i;
    *reinterpret_cast<f32x4*>(
        P1 + ((size_t)(m * 4 + kq) * 64 + b) * A_DIM + threadIdx.x * 4) = acc[i];
  }
}

// K1b: df_all[m][b][a] = sum_kq P1 + bias_m[a]
__global__ __launch_bounds__(256) void k1b_reduce(
    const float* __restrict__ P1,
    const float* __restrict__ b1, const float* __restrict__ b2,
    const float* __restrict__ b3, const float* __restrict__ b4,
    float* __restrict__ df_all) {
  int tid = blockIdx.x * 256 + threadIdx.x;  // 0..262143
  int a = tid & 1023;
  int m = tid >> 16;
  const float* bias = (m == 0) ? b1 : (m == 1) ? b2 : (m == 2) ? b3 : b4;
  size_t base = ((size_t)(m * 4) * 64) * 1024 + (tid & 65535);
  float s = P1[base] + P1[base + 65536] + P1[base + 2 * 65536] + P1[base + 3 * 65536];
  df_all[tid] = s + bias[a];
}

// K2: e[b,l] = sum_a v[a]*tanh(feat + df + cov*wc).
// block = (b, 64-row chunk); wave w handles 16 rows; df/v/wc cached in regs.
__global__ __launch_bounds__(256) void k2_energy(
    const float* __restrict__ enc_features, const float* __restrict__ enc_img_features,
    const float* __restrict__ coverage, const float* __restrict__ coverage_img,
    const float* __restrict__ df_all,
    const float* __restrict__ v1, const float* __restrict__ v2,
    const float* __restrict__ wc, const float* __restrict__ wci,
    const int* __restrict__ cov_set_p,
    float* __restrict__ e_all) {
  int bid  = blockIdx.x;
  int w    = threadIdx.x >> 6;
  int lane = threadIdx.x & 63;
  float covscale = (float)(*cov_set_p);
  const float *feat, *covsrc, *dfp, *vv, *wcp;
  float* eout;
  if (bid < 1024) {
    int b = bid >> 4, chunk = bid & 15;
    int row0 = chunk * 64 + w * 16;
    feat   = enc_features + ((size_t)b * 1024 + row0) * 1024;
    covsrc = coverage + (size_t)b * 1024 + row0;
    eout   = e_all + (size_t)b * 1024 + row0;
    dfp    = df_all + (size_t)b * 1024;
    vv = v1; wcp = wc;
  } else {
    int bi = bid - 1024;
    int b = bi >> 2, chunk = bi & 3;
    int row0 = chunk * 64 + w * 16;
    feat   = enc_img_features + ((size_t)b * 256 + row0) * 1024;
    covsrc = coverage_img + (size_t)b * 256 + row0;
    eout   = e_all + 65536 + (size_t)b * 256 + row0;
    dfp    = df_all + 65536 + (size_t)b * 1024;
    vv = v2; wcp = wci;
  }
  f32x4 dfv[4], vvv[4], wcv[4];
#pragma unroll
  for (int p = 0; p < 4; ++p) {
    int a = p * 256 + lane * 4;
    dfv[p] = *reinterpret_cast<const f32x4*>(dfp + a);
    vvv[p] = *reinterpret_cast<const f32x4*>(vv + a);
    wcv[p] = *reinterpret_cast<const f32x4*>(wcp + a);
  }
#pragma unroll 2
  for (int r = 0; r < 16; ++r) {
    float cov = covsrc[r] * covscale;
    float acc = 0.f;
#pragma unroll
    for (int p = 0; p < 4; ++p) {
      const f32x4* fp = reinterpret_cast<const f32x4*>(
          feat + (size_t)r * 1024 + p * 256 + lane * 4);
      f32x4 f = __builtin_nontemporal_load(fp);
      f32x4 x = f + dfv[p] + cov * wcv[p];
      acc += vvv[p].x * ftanh(x.x);
      acc += vvv[p].y * ftanh(x.y);
      acc += vvv[p].z * ftanh(x.z);
      acc += vvv[p].w * ftanh(x.w);
    }
#pragma unroll
    for (int o = 32; o > 0; o >>= 1) acc += __shfl_xor(acc, o);
    if (lane == 0) eout[r] = acc;
  }
}

// K3: per-row softmax (+mask renorm for text) + attn & coverage outputs.
__global__ __launch_bounds__(256) void k3_softmax(
    const float* __restrict__ e_all, const float* __restrict__ enc_mask,
    const float* __restrict__ coverage, const float* __restrict__ coverage_img,
    const int* __restrict__ cov_set_p,
    float* __restrict__ out) {
  __shared__ float red[8];
  int bid = blockIdx.x;
  int tid = threadIdx.x;
  float covscale = (float)(*cov_set_p);
  int nk;
  const float *e, *mask, *covin;
  float *attn_out, *cov_out;
  if (bid < 64) {
    nk = 4;
    e = e_all + (size_t)bid * 1024;
    mask = enc_mask + (size_t)bid * 1024;
    covin = coverage + (size_t)bid * 1024;
    attn_out = out + 65536 + (size_t)bid * 1024;
    cov_out  = out + 147456 + (size_t)bid * 1024;
  } else {
    int b = bid - 64;
    nk = 1;
    e = e_all + 65536 + (size_t)b * 256;
    mask = nullptr;
    covin = coverage_img + (size_t)b * 256;
    attn_out = out + 131072 + (size_t)b * 256;
    cov_out  = out + 212992 + (size_t)b * 256;
  }
  float ev[4], mv[4];
  float mx = -1e30f;
  for (int k = 0; k < nk; ++k) {
    int i = k * 256 + tid;
    ev[k] = e[i];
    mv[k] = mask ? mask[i] : 1.f;
    mx = fmaxf(mx, ev[k]);
  }
#pragma unroll
  for (int o = 32; o > 0; o >>= 1) mx = fmaxf(mx, __shfl_xor(mx, o));
  if ((tid & 63) == 0) red[tid >> 6] = mx;
  __syncthreads();
  mx = fmaxf(fmaxf(red[0], red[1]), fmaxf(red[2], red[3]));
  float pv[4];
  float s = 0.f;
  for (int k = 0; k < nk; ++k) {
    pv[k] = __expf(ev[k] - mx) * mv[k];
    s += pv[k];
  }
#pragma unroll
  for (int o = 32; o > 0; o >>= 1) s += __shfl_xor(s, o);
  if ((tid & 63) == 0) red[4 + (tid >> 6)] = s;
  __syncthreads();
  s = red[4] + red[5] + red[6] + red[7];
  float inv = 1.f / s;
  for (int k = 0; k < nk; ++k) {
    int i = k * 256 + tid;
    float at = pv[k] * inv;
    attn_out[i] = at;
    cov_out[i] = covscale * covin[i] + at;  // covscale==0 -> coverage = attn
  }
}

// K4: ctx partials. block = (b, 64-row L chunk); 256 thr * float4 = full A row.
__global__ __launch_bounds__(256) void k4_ctx_partial(
    const float* __restrict__ enc_outputs, const float* __restrict__ enc_img_outputs,
    const float* __restrict__ out, float* __restrict__ P4) {
  int bid = blockIdx.x;
  int tid = threadIdx.x;
  const float *src, *attn;
  if (bid < 1024) {
    int b = bid >> 4, c = bid & 15;
    src  = enc_outputs + ((size_t)b * 1024 + c * 64) * 1024;
    attn = out + 65536 + (size_t)b * 1024 + c * 64;
  } else {
    int bi = bid - 1024;
    int b = bi >> 2, c = bi & 3;
    src  = enc_img_outputs + ((size_t)b * 256 + c * 64) * 1024;
    attn = out + 131072 + (size_t)b * 256 + c * 64;
  }
  const f32x4* srcp = reinterpret_cast<const f32x4*>(src) + tid;
  f32x4 acc = {0.f, 0.f, 0.f, 0.f};
#pragma unroll 8
  for (int l = 0; l < 64; ++l) {
    float w = attn[l];  // wave-uniform -> s_load, sequential
    f32x4 r = __builtin_nontemporal_load(srcp + (size_t)l * 256);
    acc += w * r;
  }
  *reinterpret_cast<f32x4*>(P4 + (size_t)bid * 1024 + tid * 4) = acc;
}

// K4b: ctx_t[b][a] = sum_{16 chunks}; ctx_i[b][a] = sum_{4 chunks}
__global__ __launch_bounds__(256) void k4b_reduce(const float* __restrict__ P4,
                                                  float* __restrict__ ctx) {
  int tid = blockIdx.x * 256 + threadIdx.x;  // 0..131071
  int which = tid >> 16;
  int b = (tid >> 10) & 63;
  int a = tid & 1023;
  float s = 0.f;
  if (which == 0) {
    const float* p = P4 + ((size_t)b * 16) * 1024 + a;
#pragma unroll
    for (int c = 0; c < 16; ++c) s += p[(size_t)c * 1024];
    ctx[(size_t)b * 1024 + a] = s;
  } else {
    const float* p = P4 + ((size_t)1024 + b * 4) * 1024 + a;
#pragma unroll
    for (int c = 0; c < 4; ++c) s += p[(size_t)c * 1024];
    ctx[65536 + (size_t)b * 1024 + a] = s;
  }
}

// K5: partials of ctx_t@WA (m=0), ctx_i@WB (m=1). Same structure as K1.
__global__ __launch_bounds__(256) void k5_gemm(
    const float* __restrict__ ctx,
    const float* __restrict__ WA, const float* __restrict__ WB,
    float* __restrict__ P5) {
  int bid = blockIdx.x;            // 0..63
  int m   = bid >> 5;              // 0..1
  int bg  = (bid >> 2) & 7;
  int kq  = bid & 3;
  const float* W = m ? WB : WA;
  const float* dbase = ctx + (size_t)m * 65536 + kq * 256;
  const float* Wrow  = W + (size_t)(kq * 256) * A_DIM + threadIdx.x * 4;

  f32x4 acc[8];
#pragma unroll
  for (int i = 0; i < 8; ++i) acc[i] = (f32x4){0.f, 0.f, 0.f, 0.f};

  for (int k4 = 0; k4 < 256; k4 += 4) {
    f32x4 w0 = *reinterpret_cast<const f32x4*>(Wrow + (size_t)(k4 + 0) * A_DIM);
    f32x4 w1 = *reinterpret_cast<const f32x4*>(Wrow + (size_t)(k4 + 1) * A_DIM);
    f32x4 w2 = *reinterpret_cast<const f32x4*>(Wrow + (size_t)(k4 + 2) * A_DIM);
    f32x4 w3 = *reinterpret_cast<const f32x4*>(Wrow + (size_t)(k4 + 3) * A_DIM);
#pragma unroll
    for (int i = 0; i < 8; ++i) {
      int b = bg * 8 + i;
      f32x4 d = *reinterpret_cast<const f32x4*>(dbase + (size_t)b * A_DIM + k4);
      acc[i] += d.x * w0;
      acc[i] += d.y * w1;
      acc[i] += d.z * w2;
      acc[i] += d.w * w3;
    }
  }
#pragma unroll
  for (int i = 0; i < 8; ++i) {
    int b = bg * 8 + i;
    *reinterpret_cast<f32x4*>(
        P5 + ((size_t)(m * 4 + kq) * 64 + b) * A_DIM + threadIdx.x * 4) = acc[i];
  }
}

// K5b: ctx_mm = v3*tanh(g3+ctx_t@WA)*ctx_t + v4*tanh(g4+ctx_i@WB)*ctx_i
__global__ __launch_bounds__(256) void k5b_final(
    const float* __restrict__ P5, const float* __restrict__ df_all,
    const float* __restrict__ ctx,
    const float* __restrict__ v3, const float* __restrict__ v4,
    float* __restrict__ out) {
  int tid = blockIdx.x * 256 + threadIdx.x;  // 0..65535
  int a = tid & 1023;
  size_t base = tid;
  float sA = P5[base] + P5[base + 65536] + P5[base + 2 * 65536] + P5[base + 3 * 65536];
  float sB = P5[base + 4 * 65536] + P5[base + 5 * 65536] + P5[base + 6 * 65536] +
             P5[base + 7 * 65536];
  float ct = ctx[base];
  float ci = ctx[65536 + base];
  float g3v = df_all[2 * 65536 + base];
  float g4v = df_all[3 * 65536 + base];
  float beta1 = v3[a] * ftanh(g3v + sA);
  float beta2 = v4[a] * ftanh(g4v + sB);
  out[tid] = beta1 * ct + beta2 * ci;
}

extern "C" void kernel_launch(void* const* d_in, const int* in_sizes, int n_in,
                              void* d_out, int out_size, void* d_ws, size_t ws_size,
                              hipStream_t stream) {
  const float* h0            = (const float*)d_in[0];
  const float* h1            = (const float*)d_in[1];
  const float* enc_outputs   = (const float*)d_in[2];
  const float* enc_features  = (const float*)d_in[3];
  const float* enc_mask      = (const float*)d_in[4];
  const float* coverage      = (const float*)d_in[5];
  const float* enc_img_outs  = (const float*)d_in[6];
  const float* enc_img_feats = (const float*)d_in[7];
  // d_in[8] = img_mask (unused by reference)
  const float* coverage_img  = (const float*)d_in[9];
  const int*   cov_set       = (const int*)d_in[10];
  const float* W1 = (const float*)d_in[11];
  const float* b1 = (const float*)d_in[12];
  const float* W2 = (const float*)d_in[13];
  const float* b2 = (const float*)d_in[14];
  const float* W3 = (const float*)d_in[15];
  const float* b3 = (const float*)d_in[16];
  const float* W4 = (const float*)d_in[17];
  const float* b4 = (const float*)d_in[18];
  const float* WA = (const float*)d_in[19];
  const float* WB = (const float*)d_in[20];
  const float* v1 = (const float*)d_in[21];
  const float* v2 = (const float*)d_in[22];
  const float* v3 = (const float*)d_in[23];
  const float* v4 = (const float*)d_in[24];
  const float* wc  = (const float*)d_in[25];
  const float* wci = (const float*)d_in[26];

  float* out = (float*)d_out;
  float* ws  = (float*)d_ws;

  float* P      = ws;                 // P1 / P4 / P5 (lifetimes disjoint)
  float* df_all = ws + WS_DF_OFF;
  float* e_all  = ws + WS_E_OFF;
  float* ctx    = ws + WS_CTX_OFF;

  k1_gemm<<<dim3(128), dim3(256), 0, stream>>>(h0, h1, W1, W2, W3, W4, P);
  k1b_reduce<<<dim3(1024), dim3(256), 0, stream>>>(P, b1, b2, b3, b4, df_all);
  k2_energy<<<dim3(1280), dim3(256), 0, stream>>>(enc_features, enc_img_feats,
                                                  coverage, coverage_img, df_all,
                                                  v1, v2, wc, wci, cov_set, e_all);
  k3_softmax<<<dim3(128), dim3(256), 0, stream>>>(e_all, enc_mask, coverage,
                                                  coverage_img, cov_set, out);
  k4_ctx_partial<<<dim3(1280), dim3(256), 0, stream>>>(enc_outputs, enc_img_outs,
                                                       out, P);
  k4b_reduce<<<dim3(512), dim3(256), 0, stream>>>(P, ctx);
  k5_gemm<<<dim3(64), dim3(256), 0, stream>>>(ctx, WA, WB, P);
  k5b_final<<<dim3(256), dim3(256), 0, stream>>>(P, df_all, ctx, v3, v4, out);
}

// Round 4
// 192.278 us; speedup vs baseline: 2.1664x; 1.0277x over previous
//
#include <hip/hip_runtime.h>
#include <cstdint>

#define A_DIM 1024
#define B_DIM 64
#define H_DIM 512
#define L_TXT 1024
#define L_IMG 256

typedef float f32x4 __attribute__((ext_vector_type(4)));

// ---------------- ws layout (float offsets) ----------------
// region P (scratch, disjoint lifetimes):
//   P1 : 4 mats * 4 kq * 64 * 1024 = 1,048,576
//   P4 : (1024 + 256) * 1024       = 1,310,720  (max)
//   P5 : 2 mats * 4 kq * 64 * 1024 =   524,288
#define WS_DF_OFF   1310720u   // df/dfi/g3/g4 : 4*64*1024 = 262,144
#define WS_P_OFF    1572864u   // p (65536) + p_img (16384)
#define WS_CTX_OFF  1654784u   // ctx_t (65536) + ctx_i (65536)
#define WS_S_OFF    1785856u   // invS: 64 text + 64 img

// d_out layout (floats): ctx_mm[0..65535], attn[65536..131071],
// attn_img[131072..147455], coverage[147456..212991], coverage_img[212992..229375]

__device__ __forceinline__ float ftanh(float x) {
  float xc = fminf(fmaxf(x, -10.f), 10.f);
  float t  = __expf(2.f * xc);
  return (t - 1.f) * __builtin_amdgcn_rcpf(t + 1.f);
}

// K1: partials of dec @ {W1..W4}. W rows loaded VECTOR-coalesced (lane = a/4),
// dec loaded as uniform sequential s_loads. grid = 128 blocks (m, bg, kq).
__global__ __launch_bounds__(256) void k1_gemm(
    const float* __restrict__ h0, const float* __restrict__ h1,
    const float* __restrict__ W1, const float* __restrict__ W2,
    const float* __restrict__ W3, const float* __restrict__ W4,
    float* __restrict__ P1) {
  int bid = blockIdx.x;            // 0..127
  int m   = bid >> 5;              // 0..3
  int bg  = (bid >> 2) & 7;        // 0..7 (8 batch rows each)
  int kq  = bid & 3;               // 0..3 (k-quarter of 256)
  const float* W = (m == 0) ? W1 : (m == 1) ? W2 : (m == 2) ? W3 : W4;
  const float* dbase = ((kq < 2) ? h0 : h1) + (kq & 1) * 256;
  const float* Wrow  = W + (size_t)(kq * 256) * A_DIM + threadIdx.x * 4;

  f32x4 acc[8];
#pragma unroll
  for (int i = 0; i < 8; ++i) acc[i] = (f32x4){0.f, 0.f, 0.f, 0.f};

  for (int k4 = 0; k4 < 256; k4 += 4) {
    f32x4 w0 = *reinterpret_cast<const f32x4*>(Wrow + (size_t)(k4 + 0) * A_DIM);
    f32x4 w1 = *reinterpret_cast<const f32x4*>(Wrow + (size_t)(k4 + 1) * A_DIM);
    f32x4 w2 = *reinterpret_cast<const f32x4*>(Wrow + (size_t)(k4 + 2) * A_DIM);
    f32x4 w3 = *reinterpret_cast<const f32x4*>(Wrow + (size_t)(k4 + 3) * A_DIM);
#pragma unroll
    for (int i = 0; i < 8; ++i) {
      int b = bg * 8 + i;
      f32x4 d = *reinterpret_cast<const f32x4*>(dbase + (size_t)b * H_DIM + k4);
      acc[i] += d.x * w0;
      acc[i] += d.y * w1;
      acc[i] += d.z * w2;
      acc[i] += d.w * w3;
    }
  }
#pragma unroll
  for (int i = 0; i < 8; ++i) {
    int b = bg * 8 + i;
    *reinterpret_cast<f32x4*>(
        P1 + ((size_t)(m * 4 + kq) * 64 + b) * A_DIM + threadIdx.x * 4) = acc[i];
  }
}

// K1b: df_all[m][b][a] = sum_kq P1 + bias_m[a]
__global__ __launch_bounds__(256) void k1b_reduce(
    const float* __restrict__ P1,
    const float* __restrict__ b1, const float* __restrict__ b2,
    const float* __restrict__ b3, const float* __restrict__ b4,
    float* __restrict__ df_all) {
  int tid = blockIdx.x * 256 + threadIdx.x;  // 0..262143
  int a = tid & 1023;
  int m = tid >> 16;
  const float* bias = (m == 0) ? b1 : (m == 1) ? b2 : (m == 2) ? b3 : b4;
  size_t base = ((size_t)(m * 4) * 64) * 1024 + (tid & 65535);
  float s = P1[base] + P1[base + 65536] + P1[base + 2 * 65536] + P1[base + 3 * 65536];
  df_all[tid] = s + bias[a];
}

// K24 (fused energy + ctx-partial): per block (b, 64-row chunk):
//   Phase A: each wave computes e for 16 rows, then p = exp(e - V)*mask with
//            the FIXED shift V = sum_a |v_a| (>= e always, so exp<=1).
//            p -> LDS + global p_all.
//   Phase B: ctx partial with unnormalized p: P4[chunk] = sum_l p_l * out_row_l.
// Normalization by S=sum(p) happens downstream (k3 computes invS, k4b applies).
__global__ __launch_bounds__(256) void k24_fused(
    const float* __restrict__ enc_features, const float* __restrict__ enc_img_features,
    const float* __restrict__ enc_outputs,  const float* __restrict__ enc_img_outputs,
    const float* __restrict__ coverage, const float* __restrict__ coverage_img,
    const float* __restrict__ enc_mask,
    const float* __restrict__ df_all,
    const float* __restrict__ v1, const float* __restrict__ v2,
    const float* __restrict__ wc, const float* __restrict__ wci,
    const int* __restrict__ cov_set_p,
    float* __restrict__ p_all, float* __restrict__ P4) {
  __shared__ float pl[64];
  int bid  = blockIdx.x;
  int w    = threadIdx.x >> 6;
  int lane = threadIdx.x & 63;
  float covscale = (float)(*cov_set_p);
  const float *feat, *osrc, *covsrc, *dfp, *vv, *wcp, *msk;
  float* pout;
  if (bid < 1024) {
    int b = bid >> 4, chunk = bid & 15;
    int row0 = chunk * 64;
    feat   = enc_features + ((size_t)b * 1024 + row0) * 1024;
    osrc   = enc_outputs  + ((size_t)b * 1024 + row0) * 1024;
    covsrc = coverage + (size_t)b * 1024 + row0;
    msk    = enc_mask + (size_t)b * 1024 + row0;
    pout   = p_all + (size_t)b * 1024 + row0;
    dfp    = df_all + (size_t)b * 1024;
    vv = v1; wcp = wc;
  } else {
    int bi = bid - 1024;
    int b = bi >> 2, chunk = bi & 3;
    int row0 = chunk * 64;
    feat   = enc_img_features + ((size_t)b * 256 + row0) * 1024;
    osrc   = enc_img_outputs  + ((size_t)b * 256 + row0) * 1024;
    covsrc = coverage_img + (size_t)b * 256 + row0;
    msk    = nullptr;
    pout   = p_all + 65536 + (size_t)b * 256 + row0;
    dfp    = df_all + 65536 + (size_t)b * 1024;
    vv = v2; wcp = wci;
  }
  // ---- Phase A ----
  f32x4 dfv[4], vvv[4], wcv[4];
#pragma unroll
  for (int p = 0; p < 4; ++p) {
    int a = p * 256 + lane * 4;
    dfv[p] = *reinterpret_cast<const f32x4*>(dfp + a);
    vvv[p] = *reinterpret_cast<const f32x4*>(vv + a);
    wcv[p] = *reinterpret_cast<const f32x4*>(wcp + a);
  }
  // V = sum_a |v_a| : identical deterministic computation in every wave.
  float Vp = 0.f;
#pragma unroll
  for (int p = 0; p < 4; ++p)
    Vp += fabsf(vvv[p].x) + fabsf(vvv[p].y) + fabsf(vvv[p].z) + fabsf(vvv[p].w);
#pragma unroll
  for (int o = 32; o > 0; o >>= 1) Vp += __shfl_xor(Vp, o);
  float V = Vp;

#pragma unroll 2
  for (int r = 0; r < 16; ++r) {
    int row = w * 16 + r;
    float cov = covsrc[row] * covscale;
    float acc = 0.f;
#pragma unroll
    for (int p = 0; p < 4; ++p) {
      const f32x4* fp = reinterpret_cast<const f32x4*>(
          feat + (size_t)row * 1024 + p * 256 + lane * 4);
      f32x4 f = __builtin_nontemporal_load(fp);
      f32x4 x = f + dfv[p] + cov * wcv[p];
      acc += vvv[p].x * ftanh(x.x);
      acc += vvv[p].y * ftanh(x.y);
      acc += vvv[p].z * ftanh(x.z);
      acc += vvv[p].w * ftanh(x.w);
    }
#pragma unroll
    for (int o = 32; o > 0; o >>= 1) acc += __shfl_xor(acc, o);
    if (lane == 0) {
      float m = msk ? msk[row] : 1.f;
      float p = __expf(acc - V) * m;
      pl[row] = p;
      pout[row] = p;
    }
  }
  __syncthreads();
  // ---- Phase B ----
  const f32x4* srcp = reinterpret_cast<const f32x4*>(osrc) + threadIdx.x;
  f32x4 acc4 = {0.f, 0.f, 0.f, 0.f};
#pragma unroll 8
  for (int l = 0; l < 64; ++l) {
    float wt = pl[l];  // LDS broadcast
    f32x4 r = __builtin_nontemporal_load(srcp + (size_t)l * 256);
    acc4 += wt * r;
  }
  *reinterpret_cast<f32x4*>(P4 + (size_t)bid * 1024 + threadIdx.x * 4) = acc4;
}

// K3: row sums of p -> invS; attn = p*invS; coverage outputs.
__global__ __launch_bounds__(256) void k3_norm(
    const float* __restrict__ p_all,
    const float* __restrict__ coverage, const float* __restrict__ coverage_img,
    const int* __restrict__ cov_set_p,
    float* __restrict__ out, float* __restrict__ invS) {
  __shared__ float red[4];
  int bid = blockIdx.x;
  int tid = threadIdx.x;
  float covscale = (float)(*cov_set_p);
  int nk;
  const float *p, *covin;
  float *attn_out, *cov_out;
  if (bid < 64) {
    nk = 4;
    p = p_all + (size_t)bid * 1024;
    covin = coverage + (size_t)bid * 1024;
    attn_out = out + 65536 + (size_t)bid * 1024;
    cov_out  = out + 147456 + (size_t)bid * 1024;
  } else {
    int b = bid - 64;
    nk = 1;
    p = p_all + 65536 + (size_t)b * 256;
    covin = coverage_img + (size_t)b * 256;
    attn_out = out + 131072 + (size_t)b * 256;
    cov_out  = out + 212992 + (size_t)b * 256;
  }
  float pv[4];
  float s = 0.f;
  for (int k = 0; k < nk; ++k) {
    pv[k] = p[k * 256 + tid];
    s += pv[k];
  }
#pragma unroll
  for (int o = 32; o > 0; o >>= 1) s += __shfl_xor(s, o);
  if ((tid & 63) == 0) red[tid >> 6] = s;
  __syncthreads();
  s = red[0] + red[1] + red[2] + red[3];
  float inv = 1.f / s;
  if (tid == 0) invS[bid] = inv;
  for (int k = 0; k < nk; ++k) {
    int i = k * 256 + tid;
    float at = pv[k] * inv;
    attn_out[i] = at;
    cov_out[i] = covscale * covin[i] + at;  // covscale==0 -> coverage = attn
  }
}

// K4b: ctx_t[b][a] = invS_b * sum_{16 chunks}; ctx_i[b][a] = invS * sum_{4 chunks}
__global__ __launch_bounds__(256) void k4b_reduce(const float* __restrict__ P4,
                                                  const float* __restrict__ invS,
                                                  float* __restrict__ ctx) {
  int tid = blockIdx.x * 256 + threadIdx.x;  // 0..131071
  int which = tid >> 16;
  int b = (tid >> 10) & 63;
  int a = tid & 1023;
  float s = 0.f;
  if (which == 0) {
    const float* p = P4 + ((size_t)b * 16) * 1024 + a;
#pragma unroll
    for (int c = 0; c < 16; ++c) s += p[(size_t)c * 1024];
    ctx[(size_t)b * 1024 + a] = s * invS[b];
  } else {
    const float* p = P4 + ((size_t)1024 + b * 4) * 1024 + a;
#pragma unroll
    for (int c = 0; c < 4; ++c) s += p[(size_t)c * 1024];
    ctx[65536 + (size_t)b * 1024 + a] = s * invS[64 + b];
  }
}

// K5: partials of ctx_t@WA (m=0), ctx_i@WB (m=1). Same structure as K1.
__global__ __launch_bounds__(256) void k5_gemm(
    const float* __restrict__ ctx,
    const float* __restrict__ WA, const float* __restrict__ WB,
    float* __restrict__ P5) {
  int bid = blockIdx.x;            // 0..63
  int m   = bid >> 5;              // 0..1
  int bg  = (bid >> 2) & 7;
  int kq  = bid & 3;
  const float* W = m ? WB : WA;
  const float* dbase = ctx + (size_t)m * 65536 + kq * 256;
  const float* Wrow  = W + (size_t)(kq * 256) * A_DIM + threadIdx.x * 4;

  f32x4 acc[8];
#pragma unroll
  for (int i = 0; i < 8; ++i) acc[i] = (f32x4){0.f, 0.f, 0.f, 0.f};

  for (int k4 = 0; k4 < 256; k4 += 4) {
    f32x4 w0 = *reinterpret_cast<const f32x4*>(Wrow + (size_t)(k4 + 0) * A_DIM);
    f32x4 w1 = *reinterpret_cast<const f32x4*>(Wrow + (size_t)(k4 + 1) * A_DIM);
    f32x4 w2 = *reinterpret_cast<const f32x4*>(Wrow + (size_t)(k4 + 2) * A_DIM);
    f32x4 w3 = *reinterpret_cast<const f32x4*>(Wrow + (size_t)(k4 + 3) * A_DIM);
#pragma unroll
    for (int i = 0; i < 8; ++i) {
      int b = bg * 8 + i;
      f32x4 d = *reinterpret_cast<const f32x4*>(dbase + (size_t)b * A_DIM + k4);
      acc[i] += d.x * w0;
      acc[i] += d.y * w1;
      acc[i] += d.z * w2;
      acc[i] += d.w * w3;
    }
  }
#pragma unroll
  for (int i = 0; i < 8; ++i) {
    int b = bg * 8 + i;
    *reinterpret_cast<f32x4*>(
        P5 + ((size_t)(m * 4 + kq) * 64 + b) * A_DIM + threadIdx.x * 4) = acc[i];
  }
}

// K5b: ctx_mm = v3*tanh(g3+ctx_t@WA)*ctx_t + v4*tanh(g4+ctx_i@WB)*ctx_i
__global__ __launch_bounds__(256) void k5b_final(
    const float* __restrict__ P5, const float* __restrict__ df_all,
    const float* __restrict__ ctx,
    const float* __restrict__ v3, const float* __restrict__ v4,
    float* __restrict__ out) {
  int tid = blockIdx.x * 256 + threadIdx.x;  // 0..65535
  int a = tid & 1023;
  size_t base = tid;
  float sA = P5[base] + P5[base + 65536] + P5[base + 2 * 65536] + P5[base + 3 * 65536];
  float sB = P5[base + 4 * 65536] + P5[base + 5 * 65536] + P5[base + 6 * 65536] +
             P5[base + 7 * 65536];
  float ct = ctx[base];
  float ci = ctx[65536 + base];
  float g3v = df_all[2 * 65536 + base];
  float g4v = df_all[3 * 65536 + base];
  float beta1 = v3[a] * ftanh(g3v + sA);
  float beta2 = v4[a] * ftanh(g4v + sB);
  out[tid] = beta1 * ct + beta2 * ci;
}

extern "C" void kernel_launch(void* const* d_in, const int* in_sizes, int n_in,
                              void* d_out, int out_size, void* d_ws, size_t ws_size,
                              hipStream_t stream) {
  const float* h0            = (const float*)d_in[0];
  const float* h1            = (const float*)d_in[1];
  const float* enc_outputs   = (const float*)d_in[2];
  const float* enc_features  = (const float*)d_in[3];
  const float* enc_mask      = (const float*)d_in[4];
  const float* coverage      = (const float*)d_in[5];
  const float* enc_img_outs  = (const float*)d_in[6];
  const float* enc_img_feats = (const float*)d_in[7];
  // d_in[8] = img_mask (unused by reference)
  const float* coverage_img  = (const float*)d_in[9];
  const int*   cov_set       = (const int*)d_in[10];
  const float* W1 = (const float*)d_in[11];
  const float* b1 = (const float*)d_in[12];
  const float* W2 = (const float*)d_in[13];
  const float* b2 = (const float*)d_in[14];
  const float* W3 = (const float*)d_in[15];
  const float* b3 = (const float*)d_in[16];
  const float* W4 = (const float*)d_in[17];
  const float* b4 = (const float*)d_in[18];
  const float* WA = (const float*)d_in[19];
  const float* WB = (const float*)d_in[20];
  const float* v1 = (const float*)d_in[21];
  const float* v2 = (const float*)d_in[22];
  const float* v3 = (const float*)d_in[23];
  const float* v4 = (const float*)d_in[24];
  const float* wc  = (const float*)d_in[25];
  const float* wci = (const float*)d_in[26];

  float* out = (float*)d_out;
  float* ws  = (float*)d_ws;

  float* P      = ws;                 // P1 / P4 / P5 (lifetimes disjoint)
  float* df_all = ws + WS_DF_OFF;
  float* p_all  = ws + WS_P_OFF;
  float* ctx    = ws + WS_CTX_OFF;
  float* invS   = ws + WS_S_OFF;

  k1_gemm<<<dim3(128), dim3(256), 0, stream>>>(h0, h1, W1, W2, W3, W4, P);
  k1b_reduce<<<dim3(1024), dim3(256), 0, stream>>>(P, b1, b2, b3, b4, df_all);
  k24_fused<<<dim3(1280), dim3(256), 0, stream>>>(
      enc_features, enc_img_feats, enc_outputs, enc_img_outs,
      coverage, coverage_img, enc_mask, df_all,
      v1, v2, wc, wci, cov_set, p_all, P);
  k3_norm<<<dim3(128), dim3(256), 0, stream>>>(p_all, coverage, coverage_img,
                                               cov_set, out, invS);
  k4b_reduce<<<dim3(512), dim3(256), 0, stream>>>(P, invS, ctx);
  k5_gemm<<<dim3(64), dim3(256), 0, stream>>>(ctx, WA, WB, P);
  k5b_final<<<dim3(256), dim3(256), 0, stream>>>(P, df_all, ctx, v3, v4, out);
}